// Round 1
// baseline (991.147 us; speedup 1.0000x reference)
//
#include <hip/hip_runtime.h>
#include <hip/hip_bf16.h>
#include <math.h>

// ---------------- K1: degree count (in-degree via dst) ----------------
__global__ void k_deg(const int* __restrict__ dst, float* __restrict__ deg, int E) {
    int e = blockIdx.x * blockDim.x + threadIdx.x;
    if (e < E) atomicAdd(&deg[dst[e]], 1.0f);
}

// ---------------- K2: h1 = x @ W1  (N x 512) @ (512 x 16); also dinv = rsqrt(deg+1)
// wave-per-row: lane = (g,j), g=lane>>4 selects k-slice [g*128, g*128+128), j=lane&15 output col.
// W1 slice kept in 128 VGPRs per lane; x row staged to per-wave LDS for broadcast b128 reads.
__global__ __launch_bounds__(256) void k_gemm1(
    const float* __restrict__ x, const float* __restrict__ W1,
    const float* __restrict__ deg, float* __restrict__ h1,
    float* __restrict__ dinv, int N)
{
    __shared__ float4 lds4[4][128];
    const int lane = threadIdx.x & 63;
    const int wid  = threadIdx.x >> 6;
    const int g = lane >> 4, j = lane & 15;
    const int gwave  = blockIdx.x * 4 + wid;
    const int nwaves = gridDim.x * 4;

    float w[128];
    #pragma unroll
    for (int t = 0; t < 128; ++t) w[t] = W1[(g * 128 + t) * 16 + j];

    float* buf = (float*)lds4[wid];
    int row = gwave;
    if (row >= N) return;
    {
        const float4* xr = (const float4*)(x + (size_t)row * 512);
        float4 a = xr[lane], b = xr[lane + 64];
        while (row < N) {
            int nrow = row + nwaves;
            float4 a2, b2;
            if (nrow < N) {
                const float4* xr2 = (const float4*)(x + (size_t)nrow * 512);
                a2 = xr2[lane]; b2 = xr2[lane + 64];
            }
            ((float4*)buf)[lane]      = a;
            ((float4*)buf)[lane + 64] = b;
            asm volatile("s_waitcnt lgkmcnt(0)" ::: "memory");
            const float4* bx = (const float4*)(buf + g * 128);
            float acc = 0.f;
            #pragma unroll
            for (int s = 0; s < 32; ++s) {
                float4 xv = bx[s];
                acc = fmaf(xv.x, w[4*s+0], acc);
                acc = fmaf(xv.y, w[4*s+1], acc);
                acc = fmaf(xv.z, w[4*s+2], acc);
                acc = fmaf(xv.w, w[4*s+3], acc);
            }
            acc += __shfl_xor(acc, 16);
            acc += __shfl_xor(acc, 32);
            if (lane < 16) h1[(size_t)row * 16 + j] = acc;
            if (lane == 0) dinv[row] = rsqrtf(deg[row] + 1.0f);
            asm volatile("s_waitcnt lgkmcnt(0)" ::: "memory");
            row = nrow;
            a = a2; b = b2;
        }
    }
}

// ---------------- K3: agg1[d][j] += h1[s][j]*dinv[s]*dinv[d]  (edge-parallel, 16 lanes/edge)
__global__ void k_agg1(const int* __restrict__ src, const int* __restrict__ dst,
                       const float* __restrict__ dinv, const float* __restrict__ h1,
                       float* __restrict__ agg1, int E)
{
    int tid = blockIdx.x * blockDim.x + threadIdx.x;
    int stride = gridDim.x * blockDim.x;
    int total = E * 16;
    for (int idx = tid; idx < total; idx += stride) {
        int e = idx >> 4, jj = idx & 15;
        int s = src[e], d = dst[e];
        float nrm = dinv[s] * dinv[d];
        atomicAdd(&agg1[(size_t)d * 16 + jj], h1[(size_t)s * 16 + jj] * nrm);
    }
}

// ---------------- K4: x1 = elu(agg1 + h1*dinv^2 + b1); h2 = x1 @ W2  (wave-per-node)
__global__ __launch_bounds__(256) void k_layer2(
    const float* __restrict__ agg1, const float* __restrict__ h1,
    const float* __restrict__ dinv, const float* __restrict__ b1,
    const float* __restrict__ W2, float* __restrict__ h2, int N)
{
    const int lane = threadIdx.x & 63;
    const int wid  = threadIdx.x >> 6;
    const int gwave  = blockIdx.x * 4 + wid;
    const int nwaves = gridDim.x * 4;
    const int j16 = lane & 15;
    const int c = lane < 40 ? lane : 39;
    float w2[16];
    #pragma unroll
    for (int t = 0; t < 16; ++t) w2[t] = W2[t * 40 + c];
    const float b1v = b1[j16];
    for (int n = gwave; n < N; n += nwaves) {
        float dv = dinv[n], d2 = dv * dv;
        float xv = agg1[(size_t)n * 16 + j16] + h1[(size_t)n * 16 + j16] * d2 + b1v;
        xv = xv > 0.f ? xv : expm1f(xv);   // jax.nn.elu, alpha=1
        float acc = 0.f;
        #pragma unroll
        for (int t = 0; t < 16; ++t)
            acc = fmaf(__shfl(xv, t), w2[t], acc);
        if (lane < 40) h2[(size_t)n * 40 + lane] = acc;
    }
}

// ---------------- K5: out[d][c] += h2[s][c]*dinv[s]*dinv[d]  (edge-parallel, flattened E*40)
__global__ void k_agg2(const int* __restrict__ src, const int* __restrict__ dst,
                       const float* __restrict__ dinv, const float* __restrict__ h2,
                       float* __restrict__ out, int E)
{
    int tid = blockIdx.x * blockDim.x + threadIdx.x;
    int stride = gridDim.x * blockDim.x;
    int total = E * 40;
    for (int idx = tid; idx < total; idx += stride) {
        unsigned u = (unsigned)idx;
        int e = (int)(u / 40u);
        int c = (int)(u - (unsigned)e * 40u);
        int s = src[e], d = dst[e];
        atomicAdd(&out[(size_t)d * 40 + c], h2[(size_t)s * 40 + c] * dinv[s] * dinv[d]);
    }
}

// ---------------- K6: out = log_softmax(out + h2*dinv^2 + b2)  (wave-per-node, in place)
__global__ __launch_bounds__(256) void k_lsm(
    float* __restrict__ out, const float* __restrict__ h2,
    const float* __restrict__ dinv, const float* __restrict__ b2, int N)
{
    const int lane = threadIdx.x & 63;
    const int wid  = threadIdx.x >> 6;
    const int gwave  = blockIdx.x * 4 + wid;
    const int nwaves = gridDim.x * 4;
    const int c = lane < 40 ? lane : 39;
    const float b2v = b2[c];
    for (int n = gwave; n < N; n += nwaves) {
        float dv = dinv[n], d2 = dv * dv;
        float v = out[(size_t)n * 40 + c] + h2[(size_t)n * 40 + c] * d2 + b2v;
        float vm = (lane < 40) ? v : -INFINITY;
        #pragma unroll
        for (int off = 32; off; off >>= 1) vm = fmaxf(vm, __shfl_xor(vm, off));
        float ex = (lane < 40) ? expf(v - vm) : 0.f;
        float sum = ex;
        #pragma unroll
        for (int off = 32; off; off >>= 1) sum += __shfl_xor(sum, off);
        if (lane < 40) out[(size_t)n * 40 + lane] = v - vm - logf(sum);
    }
}

extern "C" void kernel_launch(void* const* d_in, const int* in_sizes, int n_in,
                              void* d_out, int out_size, void* d_ws, size_t ws_size,
                              hipStream_t stream) {
    const float* x  = (const float*)d_in[0];
    const float* W1 = (const float*)d_in[1];
    const float* b1 = (const float*)d_in[2];
    const float* W2 = (const float*)d_in[3];
    const float* b2 = (const float*)d_in[4];
    const int*   ei = (const int*)d_in[5];

    const int N = in_sizes[0] / 512;     // 100000
    const int E = in_sizes[5] / 2;       // 3200000
    const int* src = ei;
    const int* dst = ei + E;

    float* w    = (float*)d_ws;
    float* deg  = w;                      // N
    float* dinv = w + (size_t)N;          // N
    float* h1   = w + (size_t)2 * N;      // 16N
    float* agg1 = w + (size_t)18 * N;     // 16N
    float* h2   = w + (size_t)34 * N;     // 40N  (total 74N floats ~ 29.6 MB)
    float* out  = (float*)d_out;          // 40N, used as agg2 accumulator

    hipMemsetAsync(deg,  0, (size_t)N * sizeof(float), stream);
    hipMemsetAsync(agg1, 0, (size_t)N * 16 * sizeof(float), stream);
    hipMemsetAsync(out,  0, (size_t)N * 40 * sizeof(float), stream);

    k_deg   <<<(E + 255) / 256, 256, 0, stream>>>(dst, deg, E);
    k_gemm1 <<<1024, 256, 0, stream>>>(x, W1, deg, h1, dinv, N);
    k_agg1  <<<2048, 256, 0, stream>>>(src, dst, dinv, h1, agg1, E);
    k_layer2<<<1024, 256, 0, stream>>>(agg1, h1, dinv, b1, W2, h2, N);
    k_agg2  <<<4096, 256, 0, stream>>>(src, dst, dinv, h2, out, E);
    k_lsm   <<<2048, 256, 0, stream>>>(out, h2, dinv, b2, N);
}

// Round 2
// 622.363 us; speedup vs baseline: 1.5926x; 1.5926x over previous
//
#include <hip/hip_runtime.h>
#include <hip/hip_bf16.h>
#include <math.h>

// ---------------- K1: in-degree histogram (int) ----------------
__global__ void k_deg(const int* __restrict__ dst, int* __restrict__ deg, int E) {
    int e = blockIdx.x * blockDim.x + threadIdx.x;
    if (e < E) atomicAdd(&deg[dst[e]], 1);
}

// ---------------- scan phase 1: per-1024-block partial sums ----------------
__global__ void k_scan1(const int* __restrict__ deg, int* __restrict__ partial, int N) {
    int b = blockIdx.x, tid = threadIdx.x;
    int gbase = b * 1024 + tid * 4;
    int s = 0;
    if (gbase + 3 < N) {
        int4 v = *(const int4*)(deg + gbase);
        s = v.x + v.y + v.z + v.w;
    } else {
        for (int k = 0; k < 4; ++k) { int g = gbase + k; if (g < N) s += deg[g]; }
    }
    __shared__ int sm[256];
    sm[tid] = s; __syncthreads();
    for (int off = 128; off; off >>= 1) { if (tid < off) sm[tid] += sm[tid + off]; __syncthreads(); }
    if (tid == 0) partial[b] = sm[0];
}

// ---------------- scan phase 2: exclusive scan of partials (single block) ----------------
__global__ void k_scan2(int* __restrict__ partial, int* __restrict__ offs, int NB, int N, int E) {
    int tid = threadIdx.x;             // blockDim = 128, NB <= 128
    __shared__ int sm[128];
    int v = (tid < NB) ? partial[tid] : 0;
    sm[tid] = v; __syncthreads();
    for (int off = 1; off < 128; off <<= 1) {
        int t = (tid >= off) ? sm[tid - off] : 0;
        __syncthreads();
        sm[tid] += t;
        __syncthreads();
    }
    if (tid < NB) partial[tid] = sm[tid] - v;   // exclusive
    if (tid == 0) offs[N] = E;
}

// ---------------- scan phase 3: per-element exclusive scan -> offsets ----------------
__global__ void k_scan3(const int* __restrict__ deg, const int* __restrict__ partial,
                        int* __restrict__ offs, int N) {
    int b = blockIdx.x, tid = threadIdx.x;
    int gbase = b * 1024 + tid * 4;
    int v0 = 0, v1 = 0, v2 = 0, v3 = 0;
    if (gbase + 3 < N) {
        int4 v = *(const int4*)(deg + gbase);
        v0 = v.x; v1 = v.y; v2 = v.z; v3 = v.w;
    } else {
        if (gbase     < N) v0 = deg[gbase];
        if (gbase + 1 < N) v1 = deg[gbase + 1];
        if (gbase + 2 < N) v2 = deg[gbase + 2];
        if (gbase + 3 < N) v3 = deg[gbase + 3];
    }
    int ts = v0 + v1 + v2 + v3;
    __shared__ int sm[256];
    sm[tid] = ts; __syncthreads();
    for (int off = 1; off < 256; off <<= 1) {
        int t = (tid >= off) ? sm[tid - off] : 0;
        __syncthreads();
        sm[tid] += t;
        __syncthreads();
    }
    int ex = sm[tid] - ts + partial[b];
    if (gbase     < N) offs[gbase]     = ex;
    if (gbase + 1 < N) offs[gbase + 1] = ex + v0;
    if (gbase + 2 < N) offs[gbase + 2] = ex + v0 + v1;
    if (gbase + 3 < N) offs[gbase + 3] = ex + v0 + v1 + v2;
}

// ---------------- scatter edges into CSR slots ----------------
__global__ void k_scatter(const int* __restrict__ src, const int* __restrict__ dst,
                          const int* __restrict__ offs, int* __restrict__ cur,
                          int* __restrict__ csr, int E) {
    int e = blockIdx.x * blockDim.x + threadIdx.x;
    if (e < E) {
        int d = dst[e];
        int pos = offs[d] + atomicAdd(&cur[d], 1);
        csr[pos] = src[e];
    }
}

// ---------------- K2: h1s = (x @ W1) * dinv  (wave-per-row), also writes dinv
__global__ __launch_bounds__(256) void k_gemm1(
    const float* __restrict__ x, const float* __restrict__ W1,
    const int* __restrict__ deg, float* __restrict__ h1s,
    float* __restrict__ dinv, int N)
{
    __shared__ float4 lds4[4][128];
    const int lane = threadIdx.x & 63;
    const int wid  = threadIdx.x >> 6;
    const int g = lane >> 4, j = lane & 15;
    const int gwave  = blockIdx.x * 4 + wid;
    const int nwaves = gridDim.x * 4;

    float w[128];
    #pragma unroll
    for (int t = 0; t < 128; ++t) w[t] = W1[(g * 128 + t) * 16 + j];

    float* buf = (float*)lds4[wid];
    int row = gwave;
    if (row >= N) return;
    const float4* xr = (const float4*)(x + (size_t)row * 512);
    float4 a = xr[lane], b = xr[lane + 64];
    while (row < N) {
        int nrow = row + nwaves;
        float4 a2, b2;
        if (nrow < N) {
            const float4* xr2 = (const float4*)(x + (size_t)nrow * 512);
            a2 = xr2[lane]; b2 = xr2[lane + 64];
        }
        ((float4*)buf)[lane]      = a;
        ((float4*)buf)[lane + 64] = b;
        asm volatile("s_waitcnt lgkmcnt(0)" ::: "memory");
        const float4* bx = (const float4*)(buf + g * 128);
        float acc = 0.f;
        #pragma unroll
        for (int s = 0; s < 32; ++s) {
            float4 xv = bx[s];
            acc = fmaf(xv.x, w[4*s+0], acc);
            acc = fmaf(xv.y, w[4*s+1], acc);
            acc = fmaf(xv.z, w[4*s+2], acc);
            acc = fmaf(xv.w, w[4*s+3], acc);
        }
        acc += __shfl_xor(acc, 16);
        acc += __shfl_xor(acc, 32);
        float dv = rsqrtf((float)deg[row] + 1.0f);
        if (lane < 16) h1s[(size_t)row * 16 + j] = acc * dv;
        if (lane == 0) dinv[row] = dv;
        asm volatile("s_waitcnt lgkmcnt(0)" ::: "memory");
        row = nrow;
        a = a2; b = b2;
    }
}

// ---------------- K3: fused agg1 + ELU + bias1 + GEMM2 (wave-per-node) ----------------
// acc_j = sum_{s in nbr(n)} h1s[s][j];  x1 = elu((acc + h1s[n])*dinv[n] + b1)
// h2s[n] = (x1 @ W2) * dinv[n]
__global__ __launch_bounds__(256) void k_l1(
    const int* __restrict__ offs, const int* __restrict__ csr,
    const float* __restrict__ h1s, const float* __restrict__ dinv,
    const float* __restrict__ b1, const float* __restrict__ W2,
    float* __restrict__ h2s, int N)
{
    const int lane = threadIdx.x & 63;
    const int wid  = threadIdx.x >> 6;
    const int q = lane >> 4, j = lane & 15;
    const int c = lane < 40 ? lane : 39;
    const int gwave  = blockIdx.x * 4 + wid;
    const int nwaves = gridDim.x * 4;

    float w2[16];
    #pragma unroll
    for (int t = 0; t < 16; ++t) w2[t] = W2[t * 40 + c];
    const float b1v = b1[j];

    for (int n = gwave; n < N; n += nwaves) {
        int o0 = offs[n], cnt = offs[n + 1] - o0;
        float acc = 0.f;
        for (int i = q; i < cnt; i += 4) {
            int s = csr[o0 + i];
            acc += h1s[(size_t)s * 16 + j];
        }
        acc += __shfl_xor(acc, 16);
        acc += __shfl_xor(acc, 32);
        float dv = dinv[n];
        float xv = (acc + h1s[(size_t)n * 16 + j]) * dv + b1v;
        xv = xv > 0.f ? xv : expm1f(xv);   // elu, alpha=1
        float a2 = 0.f;
        #pragma unroll
        for (int t = 0; t < 16; ++t)
            a2 = fmaf(__shfl(xv, t), w2[t], a2);
        if (lane < 40) h2s[(size_t)n * 40 + lane] = a2 * dv;
    }
}

// ---------------- K4: fused agg2 + bias2 + log_softmax (wave-per-node) ----------------
__global__ __launch_bounds__(256) void k_l2(
    const int* __restrict__ offs, const int* __restrict__ csr,
    const float* __restrict__ h2s, const float* __restrict__ dinv,
    const float* __restrict__ b2, float* __restrict__ out, int N)
{
    const int lane = threadIdx.x & 63;
    const int wid  = threadIdx.x >> 6;
    const int c = lane < 40 ? lane : 39;
    const int gwave  = blockIdx.x * 4 + wid;
    const int nwaves = gridDim.x * 4;
    const float b2v = b2[c];

    for (int n = gwave; n < N; n += nwaves) {
        int o0 = offs[n], cnt = offs[n + 1] - o0;
        float acc = 0.f;
        for (int cb = 0; cb < cnt; cb += 64) {
            int rem = cnt - cb;
            int sreg = (lane < rem) ? csr[o0 + cb + lane] : 0;
            int m = rem < 64 ? rem : 64;
            for (int i = 0; i < m; ++i) {
                int s = __shfl(sreg, i);
                acc += h2s[(size_t)s * 40 + c];
            }
        }
        float dv = dinv[n];
        float v = (acc + h2s[(size_t)n * 40 + c]) * dv + b2v;
        float vm = (lane < 40) ? v : -INFINITY;
        #pragma unroll
        for (int off = 32; off; off >>= 1) vm = fmaxf(vm, __shfl_xor(vm, off));
        float ex = (lane < 40) ? expf(v - vm) : 0.f;
        float sum = ex;
        #pragma unroll
        for (int off = 32; off; off >>= 1) sum += __shfl_xor(sum, off);
        if (lane < 40) out[(size_t)n * 40 + lane] = v - vm - logf(sum);
    }
}

extern "C" void kernel_launch(void* const* d_in, const int* in_sizes, int n_in,
                              void* d_out, int out_size, void* d_ws, size_t ws_size,
                              hipStream_t stream) {
    const float* x  = (const float*)d_in[0];
    const float* W1 = (const float*)d_in[1];
    const float* b1 = (const float*)d_in[2];
    const float* W2 = (const float*)d_in[3];
    const float* b2 = (const float*)d_in[4];
    const int*   ei = (const int*)d_in[5];

    const int N = in_sizes[0] / 512;     // 100000
    const int E = in_sizes[5] / 2;       // 3200000
    const int* src = ei;
    const int* dst = ei + E;

    // workspace layout (ints then floats), N is a multiple of 4
    int* deg     = (int*)d_ws;                 // N
    int* cur     = deg + N;                    // N
    int* offs    = cur + N;                    // N+1 (pad to N+4)
    int* csr     = offs + (N + 4);             // E
    int* partial = csr + E;                    // 128
    float* dinv  = (float*)(partial + 128);    // N
    float* h1s   = dinv + N;                   // 16N
    float* h2s   = h1s + (size_t)16 * N;       // 40N
    float* out   = (float*)d_out;

    const int NB = (N + 1023) / 1024;          // 98

    hipMemsetAsync(deg, 0, (size_t)N * sizeof(int), stream);
    hipMemsetAsync(cur, 0, (size_t)N * sizeof(int), stream);

    k_deg    <<<(E + 255) / 256, 256, 0, stream>>>(dst, deg, E);
    k_scan1  <<<NB, 256, 0, stream>>>(deg, partial, N);
    k_scan2  <<<1, 128, 0, stream>>>(partial, offs, NB, N, E);
    k_scan3  <<<NB, 256, 0, stream>>>(deg, partial, offs, N);
    k_scatter<<<(E + 255) / 256, 256, 0, stream>>>(src, dst, offs, cur, csr, E);
    k_gemm1  <<<1024, 256, 0, stream>>>(x, W1, deg, h1s, dinv, N);
    k_l1     <<<2048, 256, 0, stream>>>(offs, csr, h1s, dinv, b1, W2, h2s, N);
    k_l2     <<<2048, 256, 0, stream>>>(offs, csr, h2s, dinv, b2, out, N);
}